// Round 2
// baseline (195.969 us; speedup 1.0000x reference)
//
#include <hip/hip_runtime.h>
#include <math.h>

// EdgeWeightLearner, single persistent kernel with device-scope grid barriers:
//   phase 1: p_row[n] = dot(x[n], w[0:64]);  p_col[n] = dot(x[n], w[64:128])
//   phase 2: weights[e] = sigmoid(p_row[row[e]] + p_col[col[e]])
//   phase 3: out[e] = weights[e] * weights[fri[e]]

#define IN_CH 64
#define NBLK  512
#define NTHR  256
#define NTOT  (NBLK * NTHR)   // 131072 threads, all resident (2 blocks/CU needed, >=4 capacity)

__device__ __forceinline__ void grid_barrier(int* cnt, int expected) {
    __syncthreads();  // all waves' stores issued & vmcnt-drained before barrier
    if (threadIdx.x == 0) {
        // release @ agent scope: write back this XCD's L2 before signaling
        __hip_atomic_fetch_add(cnt, 1, __ATOMIC_RELEASE, __HIP_MEMORY_SCOPE_AGENT);
        // acquire @ agent scope: invalidate stale L1/L2 before proceeding
        while (__hip_atomic_load(cnt, __ATOMIC_ACQUIRE, __HIP_MEMORY_SCOPE_AGENT) < expected) {
            __builtin_amdgcn_s_sleep(4);
        }
    }
    __syncthreads();
}

__device__ __forceinline__ float fast_sigmoid(float x) {
    return 1.0f / (1.0f + __expf(-x));
}

__global__ __launch_bounds__(NTHR, 4)
void edge_weight_fused_kernel(const float* __restrict__ x,
                              const float* __restrict__ w_lin,
                              const int*  __restrict__ row,
                              const int*  __restrict__ col,
                              const int*  __restrict__ fri,
                              float* __restrict__ p_row,
                              float* __restrict__ p_col,
                              float* __restrict__ weights,
                              float* __restrict__ out,
                              int* __restrict__ cnt0,
                              int* __restrict__ cnt1,
                              int n_nodes, int n_edges) {
    const int t = blockIdx.x * NTHR + threadIdx.x;

    // ---- phase 1: node dot products, 4 lanes per node (16 floats each) ----
    {
        const int sub = t & 3;
        const float4* wr = reinterpret_cast<const float4*>(w_lin + sub * 16);
        const float4* wc = reinterpret_cast<const float4*>(w_lin + IN_CH + sub * 16);
        float4 a0 = wr[0], a1 = wr[1], a2 = wr[2], a3 = wr[3];
        float4 b0 = wc[0], b1 = wc[1], b2 = wc[2], b3 = wc[3];
        for (int node = t >> 2; node < n_nodes; node += NTOT / 4) {
            const float4* xp = reinterpret_cast<const float4*>(x + node * IN_CH + sub * 16);
            float4 x0 = xp[0], x1 = xp[1], x2 = xp[2], x3 = xp[3];
            float pr = x0.x*a0.x + x0.y*a0.y + x0.z*a0.z + x0.w*a0.w
                     + x1.x*a1.x + x1.y*a1.y + x1.z*a1.z + x1.w*a1.w
                     + x2.x*a2.x + x2.y*a2.y + x2.z*a2.z + x2.w*a2.w
                     + x3.x*a3.x + x3.y*a3.y + x3.z*a3.z + x3.w*a3.w;
            float pc = x0.x*b0.x + x0.y*b0.y + x0.z*b0.z + x0.w*b0.w
                     + x1.x*b1.x + x1.y*b1.y + x1.z*b1.z + x1.w*b1.w
                     + x2.x*b2.x + x2.y*b2.y + x2.z*b2.z + x2.w*b2.w
                     + x3.x*b3.x + x3.y*b3.y + x3.z*b3.z + x3.w*b3.w;
            pr += __shfl_xor(pr, 1, 64); pr += __shfl_xor(pr, 2, 64);
            pc += __shfl_xor(pc, 1, 64); pc += __shfl_xor(pc, 2, 64);
            if (sub == 0) { p_row[node] = pr; p_col[node] = pc; }
        }
    }

    grid_barrier(cnt0, NBLK);

    // ---- phase 2: per-edge sigmoid, 4 edges per thread ----
    for (int e0 = t * 4; e0 < n_edges; e0 += NTOT * 4) {
        if (e0 + 3 < n_edges) {
            int4 r = *reinterpret_cast<const int4*>(row + e0);
            int4 c = *reinterpret_cast<const int4*>(col + e0);
            float4 w;
            w.x = fast_sigmoid(p_row[r.x] + p_col[c.x]);
            w.y = fast_sigmoid(p_row[r.y] + p_col[c.y]);
            w.z = fast_sigmoid(p_row[r.z] + p_col[c.z]);
            w.w = fast_sigmoid(p_row[r.w] + p_col[c.w]);
            *reinterpret_cast<float4*>(weights + e0) = w;
        } else {
            for (int e = e0; e < n_edges; ++e)
                weights[e] = fast_sigmoid(p_row[row[e]] + p_col[col[e]]);
        }
    }

    grid_barrier(cnt1, NBLK);

    // ---- phase 3: out[e] = weights[e] * weights[fri[e]], 4 edges per thread ----
    for (int e0 = t * 4; e0 < n_edges; e0 += NTOT * 4) {
        if (e0 + 3 < n_edges) {
            float4 w = *reinterpret_cast<const float4*>(weights + e0);
            int4 idx = *reinterpret_cast<const int4*>(fri + e0);
            float4 o;
            o.x = w.x * weights[idx.x];
            o.y = w.y * weights[idx.y];
            o.z = w.z * weights[idx.z];
            o.w = w.w * weights[idx.w];
            *reinterpret_cast<float4*>(out + e0) = o;
        } else {
            for (int e = e0; e < n_edges; ++e)
                out[e] = weights[e] * weights[fri[e]];
        }
    }
}

extern "C" void kernel_launch(void* const* d_in, const int* in_sizes, int n_in,
                              void* d_out, int out_size, void* d_ws, size_t ws_size,
                              hipStream_t stream) {
    const float* x     = (const float*)d_in[0];   // (N_NODES, 64) f32
    const float* w_lin = (const float*)d_in[1];   // (128,) f32
    const int*   eidx  = (const int*)d_in[2];     // (2, N_EDGES) int32
    const int*   fri   = (const int*)d_in[3];     // (N_EDGES,) int32

    const int n_nodes = in_sizes[0] / IN_CH;
    const int n_edges = in_sizes[3];

    const int* row = eidx;
    const int* col = eidx + n_edges;

    // workspace layout: [cnt0 @0, cnt1 @128, pad to 256] [p_row] [p_col] [weights]
    char* ws = (char*)d_ws;
    int*   cnt0    = (int*)(ws);
    int*   cnt1    = (int*)(ws + 128);
    float* p_row   = (float*)(ws + 256);
    float* p_col   = p_row + n_nodes;
    float* weights = p_col + n_nodes;
    float* out     = (float*)d_out;

    // zero the barrier counters (d_ws is re-poisoned 0xAA before every launch)
    hipMemsetAsync(d_ws, 0, 256, stream);

    edge_weight_fused_kernel<<<NBLK, NTHR, 0, stream>>>(
        x, w_lin, row, col, fri, p_row, p_col, weights, out,
        cnt0, cnt1, n_nodes, n_edges);
}

// Round 4
// 98.010 us; speedup vs baseline: 1.9995x; 1.9995x over previous
//
#include <hip/hip_runtime.h>
#include <math.h>

// EdgeWeightLearner, 2-kernel pipeline:
//   K1: p_row[n] = dot(x[n], w[0:64]);  p_col[n] = dot(x[n], w[64:128])
//   K2 (fused): f = fri[e]
//       out[e] = sigmoid(p_row[row[e]] + p_col[col[e]])
//              * sigmoid(p_row[row[f]] + p_col[col[f]])
//   (recomputing sigmoid for edge f is identical arithmetic to gathering a
//    stored weights[f]; row/col arrays are L3-resident so the random
//    re-gather is cheap, and the 6.4 MB weights round-trip disappears.)

#define IN_CH 64

// K1: 16 lanes per node, float4 each -> 64 ch. Perfectly coalesced
// (64 lanes cover 4 nodes' contiguous 1 KiB).
__global__ void node_dots_kernel(const float* __restrict__ x,
                                 const float* __restrict__ w_lin,
                                 float* __restrict__ p_row,
                                 float* __restrict__ p_col,
                                 int n_nodes) {
    int tid = blockIdx.x * blockDim.x + threadIdx.x;
    int node = tid >> 4;
    int sub  = tid & 15;
    if (node >= n_nodes) return;
    const float4 xv = *reinterpret_cast<const float4*>(x + node * IN_CH + sub * 4);
    const float4 wr = *reinterpret_cast<const float4*>(w_lin + sub * 4);
    const float4 wc = *reinterpret_cast<const float4*>(w_lin + IN_CH + sub * 4);
    float pr = xv.x * wr.x + xv.y * wr.y + xv.z * wr.z + xv.w * wr.w;
    float pc = xv.x * wc.x + xv.y * wc.y + xv.z * wc.z + xv.w * wc.w;
    #pragma unroll
    for (int m = 1; m < 16; m <<= 1) {
        pr += __shfl_xor(pr, m, 64);
        pc += __shfl_xor(pc, m, 64);
    }
    if (sub == 0) {
        p_row[node] = pr;
        p_col[node] = pc;
    }
}

__device__ __forceinline__ float fast_sigmoid(float x) {
    return 1.0f / (1.0f + __expf(-x));
}

// K2: one edge per thread for max TLP (latency-bound gathers).
__global__ __launch_bounds__(256)
void edge_fused_kernel(const int* __restrict__ row,
                       const int* __restrict__ col,
                       const int* __restrict__ fri,
                       const float* __restrict__ p_row,
                       const float* __restrict__ p_col,
                       float* __restrict__ out,
                       int n_edges) {
    int e = blockIdx.x * blockDim.x + threadIdx.x;
    if (e >= n_edges) return;
    int r = row[e];
    int c = col[e];
    int f = fri[e];
    // issue the dependent index gathers early
    int r2 = row[f];
    int c2 = col[f];
    float w_self  = fast_sigmoid(p_row[r]  + p_col[c]);
    float w_other = fast_sigmoid(p_row[r2] + p_col[c2]);
    out[e] = w_self * w_other;
}

extern "C" void kernel_launch(void* const* d_in, const int* in_sizes, int n_in,
                              void* d_out, int out_size, void* d_ws, size_t ws_size,
                              hipStream_t stream) {
    const float* x     = (const float*)d_in[0];   // (N_NODES, 64) f32
    const float* w_lin = (const float*)d_in[1];   // (128,) f32
    const int*   eidx  = (const int*)d_in[2];     // (2, N_EDGES) int32
    const int*   fri   = (const int*)d_in[3];     // (N_EDGES,) int32

    const int n_nodes = in_sizes[0] / IN_CH;
    const int n_edges = in_sizes[3];

    const int* row = eidx;
    const int* col = eidx + n_edges;

    float* p_row = (float*)d_ws;        // n_nodes floats
    float* p_col = p_row + n_nodes;     // n_nodes floats
    float* out   = (float*)d_out;       // n_edges floats

    // K1: 16 threads per node
    {
        long long threads = (long long)n_nodes * 16;
        int block = 256;
        int grid = (int)((threads + block - 1) / block);
        node_dots_kernel<<<grid, block, 0, stream>>>(x, w_lin, p_row, p_col, n_nodes);
    }
    // K2: 1 edge per thread
    {
        int block = 256;
        int grid = (n_edges + block - 1) / block;
        edge_fused_kernel<<<grid, block, 0, stream>>>(row, col, fri, p_row, p_col, out, n_edges);
    }
}

// Round 6
// 87.751 us; speedup vs baseline: 2.2332x; 1.1169x over previous
//
#include <hip/hip_runtime.h>
#include <hip/hip_fp16.h>
#include <math.h>

// EdgeWeightLearner, 3-kernel pipeline (store-then-gather; fp16 weights):
//   K1: p_row[n] = dot(x[n], w[0:64]);  p_col[n] = dot(x[n], w[64:128])
//   K2: wh[e] = (half) sigmoid(p_row[row[e]] + p_col[col[e]])
//   K3: out[e] = (float)wh[e] * (float)wh[fri[e]]
// fp16 weights: 1.6 MB gather set (L2-resident per XCD; round-4 lesson:
// keep the random-gather working set under the 4 MiB per-XCD L2).

#define IN_CH 64

// K1: 16 lanes per node, float4 each -> 64 ch. Perfectly coalesced
// (64 lanes cover 4 nodes' contiguous 1 KiB).
__global__ void node_dots_kernel(const float* __restrict__ x,
                                 const float* __restrict__ w_lin,
                                 float* __restrict__ p_row,
                                 float* __restrict__ p_col,
                                 int n_nodes) {
    int tid = blockIdx.x * blockDim.x + threadIdx.x;
    int node = tid >> 4;
    int sub  = tid & 15;
    if (node >= n_nodes) return;
    const float4 xv = *reinterpret_cast<const float4*>(x + node * IN_CH + sub * 4);
    const float4 wr = *reinterpret_cast<const float4*>(w_lin + sub * 4);
    const float4 wc = *reinterpret_cast<const float4*>(w_lin + IN_CH + sub * 4);
    float pr = xv.x * wr.x + xv.y * wr.y + xv.z * wr.z + xv.w * wr.w;
    float pc = xv.x * wc.x + xv.y * wc.y + xv.z * wc.z + xv.w * wc.w;
    #pragma unroll
    for (int m = 1; m < 16; m <<= 1) {
        pr += __shfl_xor(pr, m, 64);
        pc += __shfl_xor(pc, m, 64);
    }
    if (sub == 0) {
        p_row[node] = pr;
        p_col[node] = pc;
    }
}

__device__ __forceinline__ float fast_sigmoid(float x) {
    return 1.0f / (1.0f + __expf(-x));
}

// K2: 8 edges/thread; coalesced int4 index loads, random p-gathers (400 KB,
// L2-resident), fp16 store (16 B/thread).
__global__ __launch_bounds__(256)
void edge_sigmoid_kernel(const int* __restrict__ row,
                         const int* __restrict__ col,
                         const float* __restrict__ p_row,
                         const float* __restrict__ p_col,
                         __half* __restrict__ wh,
                         int n_edges) {
    int e0 = (blockIdx.x * blockDim.x + threadIdx.x) * 8;
    if (e0 + 7 < n_edges) {
        int4 r0 = *reinterpret_cast<const int4*>(row + e0);
        int4 r1 = *reinterpret_cast<const int4*>(row + e0 + 4);
        int4 c0 = *reinterpret_cast<const int4*>(col + e0);
        int4 c1 = *reinterpret_cast<const int4*>(col + e0 + 4);
        float l0 = p_row[r0.x] + p_col[c0.x];
        float l1 = p_row[r0.y] + p_col[c0.y];
        float l2 = p_row[r0.z] + p_col[c0.z];
        float l3 = p_row[r0.w] + p_col[c0.w];
        float l4 = p_row[r1.x] + p_col[c1.x];
        float l5 = p_row[r1.y] + p_col[c1.y];
        float l6 = p_row[r1.z] + p_col[c1.z];
        float l7 = p_row[r1.w] + p_col[c1.w];
        __half2 h0 = __floats2half2_rn(fast_sigmoid(l0), fast_sigmoid(l1));
        __half2 h1 = __floats2half2_rn(fast_sigmoid(l2), fast_sigmoid(l3));
        __half2 h2 = __floats2half2_rn(fast_sigmoid(l4), fast_sigmoid(l5));
        __half2 h3 = __floats2half2_rn(fast_sigmoid(l6), fast_sigmoid(l7));
        __half2* dst = reinterpret_cast<__half2*>(wh + e0);
        dst[0] = h0; dst[1] = h1; dst[2] = h2; dst[3] = h3;
    } else {
        for (int e = e0; e < n_edges; ++e)
            wh[e] = __float2half(fast_sigmoid(p_row[row[e]] + p_col[col[e]]));
    }
}

// K3: 8 edges/thread; stream wh + fri, 8 independent random fp16 gathers
// into a 1.6 MB array (L2-resident), f32 store.
__global__ __launch_bounds__(256)
void edge_pair_kernel(const __half* __restrict__ wh,
                      const int* __restrict__ fri,
                      float* __restrict__ out,
                      int n_edges) {
    int e0 = (blockIdx.x * blockDim.x + threadIdx.x) * 8;
    if (e0 + 7 < n_edges) {
        const __half2* wp = reinterpret_cast<const __half2*>(wh + e0);
        __half2 w0 = wp[0], w1 = wp[1], w2 = wp[2], w3 = wp[3];
        int4 i0 = *reinterpret_cast<const int4*>(fri + e0);
        int4 i1 = *reinterpret_cast<const int4*>(fri + e0 + 4);
        float g0 = __half2float(wh[i0.x]);
        float g1 = __half2float(wh[i0.y]);
        float g2 = __half2float(wh[i0.z]);
        float g3 = __half2float(wh[i0.w]);
        float g4 = __half2float(wh[i1.x]);
        float g5 = __half2float(wh[i1.y]);
        float g6 = __half2float(wh[i1.z]);
        float g7 = __half2float(wh[i1.w]);
        float4 o0, o1;
        o0.x = __half2float(w0.x) * g0;
        o0.y = __half2float(w0.y) * g1;
        o0.z = __half2float(w1.x) * g2;
        o0.w = __half2float(w1.y) * g3;
        o1.x = __half2float(w2.x) * g4;
        o1.y = __half2float(w2.y) * g5;
        o1.z = __half2float(w3.x) * g6;
        o1.w = __half2float(w3.y) * g7;
        *reinterpret_cast<float4*>(out + e0) = o0;
        *reinterpret_cast<float4*>(out + e0 + 4) = o1;
    } else {
        for (int e = e0; e < n_edges; ++e)
            out[e] = __half2float(wh[e]) * __half2float(wh[fri[e]]);
    }
}

extern "C" void kernel_launch(void* const* d_in, const int* in_sizes, int n_in,
                              void* d_out, int out_size, void* d_ws, size_t ws_size,
                              hipStream_t stream) {
    const float* x     = (const float*)d_in[0];   // (N_NODES, 64) f32
    const float* w_lin = (const float*)d_in[1];   // (128,) f32
    const int*   eidx  = (const int*)d_in[2];     // (2, N_EDGES) int32
    const int*   fri   = (const int*)d_in[3];     // (N_EDGES,) int32

    const int n_nodes = in_sizes[0] / IN_CH;
    const int n_edges = in_sizes[3];

    const int* row = eidx;
    const int* col = eidx + n_edges;

    float*  p_row = (float*)d_ws;                 // n_nodes f32
    float*  p_col = p_row + n_nodes;              // n_nodes f32
    __half* wh    = (__half*)(p_col + n_nodes);   // n_edges fp16 (1.6 MB)
    float*  out   = (float*)d_out;                // n_edges f32

    // K1: 16 threads per node
    {
        long long threads = (long long)n_nodes * 16;
        int block = 256;
        int grid = (int)((threads + block - 1) / block);
        node_dots_kernel<<<grid, block, 0, stream>>>(x, w_lin, p_row, p_col, n_nodes);
    }
    // K2: 8 edges per thread
    {
        int block = 256;
        int grid = (n_edges / 8 + block - 1) / block;
        edge_sigmoid_kernel<<<grid, block, 0, stream>>>(row, col, p_row, p_col, wh, n_edges);
    }
    // K3: 8 edges per thread
    {
        int block = 256;
        int grid = (n_edges / 8 + block - 1) / block;
        edge_pair_kernel<<<grid, block, 0, stream>>>(wh, fri, out, n_edges);
    }
}